// Round 3
// baseline (1017.589 us; speedup 1.0000x reference)
//
#include <hip/hip_runtime.h>
#include <hip/hip_bf16.h>

// DotProductAttention: B=4, N=4096, E=1024, D=256. Inputs/outputs are FLOAT32
// (per reference setup_inputs). Internally: cast X to bf16 once, bf16 MFMA
// pipeline with fp32 accumulation, f32 output.
// Pipeline: cast/prep (Xb, WqT/WkT/WvT) -> Q,K GEMM -> VT GEMM -> fused flash
// attention (no P materialization). Workspace: 83 MB.

typedef __hip_bfloat16 bf16;
typedef __bf16 bf16x4 __attribute__((ext_vector_type(4)));
typedef __bf16 bf16x8 __attribute__((ext_vector_type(8)));
typedef float f32x4 __attribute__((ext_vector_type(4)));

#define BK 32
#define PS_LD 136  // 128 + 8 pad: 272B row stride (16B-aligned, de-conflicted)

__device__ __forceinline__ void gload_lds16(const bf16* g, bf16* l) {
    __builtin_amdgcn_global_load_lds(
        (const __attribute__((address_space(1))) unsigned int*)g,
        (__attribute__((address_space(3))) unsigned int*)l, 16, 0, 0);
}

__device__ __forceinline__ void zero_acc(f32x4 acc[4][4]) {
#pragma unroll
    for (int mi = 0; mi < 4; ++mi)
#pragma unroll
        for (int ni = 0; ni < 4; ++ni) {
            f32x4 zf = {0.f, 0.f, 0.f, 0.f};
            acc[mi][ni] = zf;
        }
}

// C-tile accumulate: acc += A[128 x K] * BT[128 x K]^T (m97 structure).
// As/Bs are caller-provided 128*BK LDS buffers. Ends with __syncthreads().
__device__ __forceinline__ void mm_tile(const bf16* __restrict__ Ablk,
                                        const bf16* __restrict__ Bblk,
                                        int lda, int ldb, int kiters,
                                        bf16* As, bf16* Bs, f32x4 acc[4][4]) {
    const int tid  = threadIdx.x;
    const int wave = tid >> 6;
    const int lane = tid & 63;

    const int F0 = wave * 2048 + lane * 16;  // byte offset; 4 waves cover 8KB
    const int F1 = F0 + 1024;
    const int r0 = F0 >> 6, c0 = (F0 & 63) >> 1;  // 64B (=32 bf16) per row
    const int r1 = F1 >> 6, c1 = (F1 & 63) >> 1;
    const bf16* ga0 = Ablk + (size_t)r0 * lda + c0;
    const bf16* ga1 = Ablk + (size_t)r1 * lda + c1;
    const bf16* gb0 = Bblk + (size_t)r0 * ldb + c0;
    const bf16* gb1 = Bblk + (size_t)r1 * ldb + c1;
    bf16* lA0 = (bf16*)((char*)As + F0);
    bf16* lA1 = (bf16*)((char*)As + F1);
    bf16* lB0 = (bf16*)((char*)Bs + F0);
    bf16* lB1 = (bf16*)((char*)Bs + F1);

    const int waveM = wave >> 1, waveN = wave & 1;
    const int mrow = waveM * 64 + (lane & 15);
    const int nrow = waveN * 64 + (lane & 15);
    const int koff = (lane >> 4) * 8;

    for (int it = 0; it < kiters; ++it) {
        gload_lds16(ga0, lA0);
        gload_lds16(ga1, lA1);
        gload_lds16(gb0, lB0);
        gload_lds16(gb1, lB1);
        ga0 += BK; ga1 += BK; gb0 += BK; gb1 += BK;
        __syncthreads();  // drains vmcnt for global_load_lds + barrier

        bf16x8 af[4], bfr[4];
#pragma unroll
        for (int mi = 0; mi < 4; ++mi)
            af[mi] = *(const bf16x8*)(As + (mrow + mi * 16) * BK + koff);
#pragma unroll
        for (int ni = 0; ni < 4; ++ni)
            bfr[ni] = *(const bf16x8*)(Bs + (nrow + ni * 16) * BK + koff);
#pragma unroll
        for (int mi = 0; mi < 4; ++mi)
#pragma unroll
            for (int ni = 0; ni < 4; ++ni)
                acc[mi][ni] = __builtin_amdgcn_mfma_f32_16x16x32_bf16(
                    af[mi], bfr[ni], acc[mi][ni], 0, 0, 0);
        __syncthreads();
    }
}

// ---------------- plain GEMM: C[m][n] = A*BT^T, bf16 store -----------------
__global__ __launch_bounds__(256, 2) void k_gemm_plain(
    const bf16* __restrict__ A, long long aBatch,
    const bf16* __restrict__ BT, long long bBatch,
    bf16* __restrict__ C, long long cBatch,
    int lda, int ldb, int ldc, int kiters) {
    __shared__ __align__(16) bf16 As[128 * BK];
    __shared__ __align__(16) bf16 Bs[128 * BK];
    const int nBase = blockIdx.x * 128;
    const int mBase = blockIdx.y * 128;
    const int z = blockIdx.z;
    const bf16* Ab = A + (size_t)z * aBatch + (size_t)mBase * lda;
    const bf16* Bb = BT + (size_t)z * bBatch + (size_t)nBase * ldb;

    f32x4 acc[4][4];
    zero_acc(acc);
    mm_tile(Ab, Bb, lda, ldb, kiters, As, Bs, acc);

    const int tid = threadIdx.x, wave = tid >> 6, lane = tid & 63;
    const int waveM = wave >> 1, waveN = wave & 1;
    const int quad = lane >> 4, cno = lane & 15;
    bf16* Cb = C + (size_t)z * cBatch;
#pragma unroll
    for (int mi = 0; mi < 4; ++mi) {
        int row0 = mBase + waveM * 64 + mi * 16 + quad * 4;
#pragma unroll
        for (int ni = 0; ni < 4; ++ni) {
            int col = nBase + waveN * 64 + ni * 16 + cno;
#pragma unroll
            for (int r = 0; r < 4; ++r)
                Cb[(size_t)(row0 + r) * ldc + col] = __float2bfloat16(acc[mi][ni][r]);
        }
    }
}

// --------------------- fused flash-style attention -------------------------
// Block = (dv-tile 128, q-tile 128, batch). For kt in [0, qt]:
//   S = Q Kt^T / 16 ; P = (causal && S!=0) ? exp(S) : 0  -> Ps (LDS, bf16)
//   lrow[q] += rowsum(P) ; O += P * Vt   (Vt staged from VT global)
// Final: out = O / lrow (f32 store). No max-shift: |S| <~ 20, exp fits f32.
__global__ __launch_bounds__(256, 2) void k_attn(
    const bf16* __restrict__ Qm, const bf16* __restrict__ Km,
    const bf16* __restrict__ VT, float* __restrict__ Out) {
    __shared__ __align__(16) bf16 Qs[128 * BK];
    __shared__ __align__(16) bf16 Ks[128 * BK];
    __shared__ __align__(16) bf16 Ps[128 * PS_LD];
    __shared__ __align__(16) bf16 Vs[128 * BK];
    __shared__ float lrow[128];

    const int dvBase = blockIdx.x * 128;
    const int qt = 31 - blockIdx.y;  // big tiles first (load balance)
    const int b = blockIdx.z;
    const int tid = threadIdx.x, wave = tid >> 6, lane = tid & 63;
    const int waveM = wave >> 1, waveN = wave & 1;
    const int quad = lane >> 4, cno = lane & 15;
    const int koff = quad * 8;

    if (tid < 128) lrow[tid] = 0.f;
    // first __syncthreads() happens inside mm_tile before any lrow atomicAdd

    f32x4 acc_o[4][4];
    zero_acc(acc_o);

    const bf16* Qtile = Qm + ((size_t)b * 4096 + (size_t)qt * 128) * 256;
    const bf16* Kbase = Km + (size_t)b * 4096 * 256;
    const bf16* Vblk  = VT + ((size_t)b * 1024 + dvBase) * 4096;

    const int F0 = wave * 2048 + lane * 16;
    const int F1 = F0 + 1024;
    const int r0 = F0 >> 6, c0 = (F0 & 63) >> 1;
    const int r1 = F1 >> 6, c1 = (F1 & 63) >> 1;

    for (int kt = 0; kt <= qt; ++kt) {
        // ---- score: S = Q * K^T over D=256 ----
        f32x4 acc_s[4][4];
        zero_acc(acc_s);
        mm_tile(Qtile, Kbase + (size_t)kt * 128 * 256, 256, 256, 256 / BK,
                Qs, Ks, acc_s);  // ends with __syncthreads()

        // ---- transform: mask + exp -> Ps (bf16), row sums -> lrow ----
#pragma unroll
        for (int mi = 0; mi < 4; ++mi) {
            const int lq0 = waveM * 64 + mi * 16 + quad * 4;
            float rs[4] = {0.f, 0.f, 0.f, 0.f};
#pragma unroll
            for (int ni = 0; ni < 4; ++ni) {
                const int cn = waveN * 64 + ni * 16 + cno;
                const int gk = kt * 128 + cn;
#pragma unroll
                for (int r = 0; r < 4; ++r) {
                    const int gq = qt * 128 + lq0 + r;
                    float s = acc_s[mi][ni][r] * 0.0625f;  // 1/sqrt(256)
                    // ref quirk: masked OR exactly-zero score -> exp = 0
                    float p = (gk <= gq && s != 0.0f) ? __expf(s) : 0.0f;
                    bf16 pb = __float2bfloat16(p);
                    Ps[(lq0 + r) * PS_LD + cn] = pb;
                    rs[r] += __bfloat162float(pb);  // sum what PV multiplies
                }
            }
#pragma unroll
            for (int r = 0; r < 4; ++r) {
                float v = rs[r];
                v += __shfl_xor(v, 1);
                v += __shfl_xor(v, 2);
                v += __shfl_xor(v, 4);
                v += __shfl_xor(v, 8);
                if (cno == 0) atomicAdd(&lrow[lq0 + r], v);
            }
        }
        __syncthreads();  // Ps complete before PV reads

        // ---- PV: O += P(128x128) * Vt^T, 4 chunks of K=32 ----
#pragma unroll
        for (int c = 0; c < 4; ++c) {
            const int kcol = kt * 128 + c * 32;
            gload_lds16(Vblk + (size_t)r0 * 4096 + kcol + c0,
                        (bf16*)((char*)Vs + F0));
            gload_lds16(Vblk + (size_t)r1 * 4096 + kcol + c1,
                        (bf16*)((char*)Vs + F1));
            __syncthreads();

            bf16x8 af[4], bfr[4];
#pragma unroll
            for (int mi = 0; mi < 4; ++mi)
                af[mi] = *(const bf16x8*)(Ps + (waveM * 64 + mi * 16 + cno) * PS_LD
                                          + c * 32 + koff);
#pragma unroll
            for (int ni = 0; ni < 4; ++ni)
                bfr[ni] = *(const bf16x8*)(Vs + (waveN * 64 + ni * 16 + cno) * BK
                                           + koff);
#pragma unroll
            for (int mi = 0; mi < 4; ++mi)
#pragma unroll
                for (int ni = 0; ni < 4; ++ni)
                    acc_o[mi][ni] = __builtin_amdgcn_mfma_f32_16x16x32_bf16(
                        af[mi], bfr[ni], acc_o[mi][ni], 0, 0, 0);
            __syncthreads();  // Vs (and Ps on last chunk) free for reuse
        }
    }

    // ---- epilogue: out = O / lrow (FLOAT32 store) ----
    float* Ob = Out + (size_t)b * 4096 * 1024;
#pragma unroll
    for (int mi = 0; mi < 4; ++mi) {
        const int lq0 = waveM * 64 + mi * 16 + quad * 4;
#pragma unroll
        for (int r = 0; r < 4; ++r) {
            const float inv = 1.0f / lrow[lq0 + r];
            const int gq = qt * 128 + lq0 + r;
#pragma unroll
            for (int ni = 0; ni < 4; ++ni) {
                const int col = dvBase + waveN * 64 + ni * 16 + cno;
                Ob[(size_t)gq * 1024 + col] = acc_o[mi][ni][r] * inv;
            }
        }
    }
}

// ----------------------------- prep kernels (f32 inputs) -------------------
// f32 -> bf16 bulk cast, 4 elements/thread
__global__ void k_cast(const float4* __restrict__ in, bf16* __restrict__ out,
                       int n4) {
    int i = blockIdx.x * 256 + threadIdx.x;
    if (i >= n4) return;
    float4 v = in[i];
    bf16x4 o;
    o[0] = (__bf16)v.x; o[1] = (__bf16)v.y; o[2] = (__bf16)v.z; o[3] = (__bf16)v.w;
    *(bf16x4*)(out + 4 * (size_t)i) = o;
}

// in[R][C] f32 -> out[C][R] bf16, R=1024
__global__ void k_transpose(const float* __restrict__ in, bf16* __restrict__ out,
                            int R, int C) {
    int idx = blockIdx.x * 256 + threadIdx.x;  // idx = c*R + r
    if (idx >= R * C) return;
    int r = idx & (R - 1);
    int c = idx >> 10;
    out[idx] = __float2bfloat16(in[(size_t)r * C + c]);
}

// WvT[dv][e] = sum_d Wvdown[e][d] * Wvup[d][dv]  (f32 math, bf16 out)
__global__ void k_wvt(const float* __restrict__ Wvdown, const float* __restrict__ Wvup,
                      bf16* __restrict__ WvT) {
    int idx = blockIdx.x * 256 + threadIdx.x;  // 1M outputs
    int e = idx & 1023;
    int dv = idx >> 10;
    float acc = 0.f;
#pragma unroll 8
    for (int d = 0; d < 256; ++d)
        acc += Wvdown[e * 256 + d] * Wvup[d * 1024 + dv];
    WvT[(size_t)dv * 1024 + e] = __float2bfloat16(acc);
}

extern "C" void kernel_launch(void* const* d_in, const int* in_sizes, int n_in,
                              void* d_out, int out_size, void* d_ws, size_t ws_size,
                              hipStream_t stream) {
    const int B = 4, N = 4096, E = 1024, D = 256;
    const float* X   = (const float*)d_in[0];  // [4,4096,1024] f32
    const float* Wq  = (const float*)d_in[1];  // [1024,256]    f32
    const float* Wk  = (const float*)d_in[2];  // [1024,256]    f32
    const float* Wvd = (const float*)d_in[3];  // [1024,256]    f32
    const float* Wvu = (const float*)d_in[4];  // [256,1024]    f32
    float* out = (float*)d_out;                // [4,4096,1024] f32

    // workspace layout: 83 MB total
    char* ws = (char*)d_ws;
    bf16* Xb  = (bf16*)(ws);                  // 32 MB [16384][1024]
    bf16* WqT = (bf16*)(ws + (32ll << 20));   // 512 KB [256][1024]
    bf16* WkT = (bf16*)(ws + (32ll << 20) + (512ll << 10));  // 512 KB (adj.)
    bf16* WvT = (bf16*)(ws + (33ll << 20));   // 2 MB  [1024][1024]
    bf16* Qm  = (bf16*)(ws + (35ll << 20));   // 8 MB  [16384][256]
    bf16* Km  = (bf16*)(ws + (43ll << 20));   // 8 MB  (adjacent to Qm)
    bf16* VT  = (bf16*)(ws + (51ll << 20));   // 32 MB [4][1024][4096]

    const int n4 = B * N * E / 4;  // 4.19M float4 groups
    k_cast<<<(n4 + 255) / 256, 256, 0, stream>>>((const float4*)X, Xb, n4);
    k_transpose<<<1024, 256, 0, stream>>>(Wq, WqT, 1024, 256);
    k_transpose<<<1024, 256, 0, stream>>>(Wk, WkT, 1024, 256);
    k_wvt<<<4096, 256, 0, stream>>>(Wvd, Wvu, WvT);

    // Q,K = Xb @ Wq / Xb @ Wk  (fused via z: BT and C strided, A shared)
    k_gemm_plain<<<dim3(D / 128, (B * N) / 128, 2), 256, 0, stream>>>(
        Xb, 0, WqT, (long long)D * E, Qm, (long long)B * N * D,
        E, E, D, E / BK);

    // VT[b] = WvT @ Xb[b]^T  (C[dv][n])
    k_gemm_plain<<<dim3(N / 128, E / 128, B), 256, 0, stream>>>(
        WvT, 0, Xb, (long long)N * E, VT, (long long)E * N,
        E, E, N, E / BK);

    // fused attention: out = softmax_causal(Q K^T / 16) @ V
    k_attn<<<dim3(E / 128, N / 128, B), 256, 0, stream>>>(Qm, Km, VT, out);
}

// Round 4
// 572.370 us; speedup vs baseline: 1.7779x; 1.7779x over previous
//
#include <hip/hip_runtime.h>
#include <hip/hip_bf16.h>

// DotProductAttention: B=4, N=4096, E=1024, D=256. f32 in/out.
// Pipeline: cast/prep -> Q,K GEMM -> VT GEMM -> k_score (packed lower-tri P~,
// rowsum l) -> k_pv (O = P~ @ V / l). P packed by row-block: block-row qt has
// pitch (qt+1)*128 -> 69 MB instead of 128 MB. Fallback to fused k_attn if
// ws_size < 150 MiB (deterministic, graph-safe).

typedef __hip_bfloat16 bf16;
typedef __bf16 bf16x4 __attribute__((ext_vector_type(4)));
typedef __bf16 bf16x8 __attribute__((ext_vector_type(8)));
typedef float f32x4 __attribute__((ext_vector_type(4)));

#define BK 32
#define PS_LD 136

__device__ __forceinline__ void gload_lds16(const bf16* g, bf16* l) {
    __builtin_amdgcn_global_load_lds(
        (const __attribute__((address_space(1))) unsigned int*)g,
        (__attribute__((address_space(3))) unsigned int*)l, 16, 0, 0);
}

__device__ __forceinline__ void zero_acc(f32x4 acc[4][4]) {
#pragma unroll
    for (int mi = 0; mi < 4; ++mi)
#pragma unroll
        for (int ni = 0; ni < 4; ++ni) {
            f32x4 zf = {0.f, 0.f, 0.f, 0.f};
            acc[mi][ni] = zf;
        }
}

// C-tile accumulate: acc += A[128 x K] * BT[128 x K]^T (m97 structure).
__device__ __forceinline__ void mm_tile(const bf16* __restrict__ Ablk,
                                        const bf16* __restrict__ Bblk,
                                        int lda, int ldb, int kiters,
                                        bf16* As, bf16* Bs, f32x4 acc[4][4]) {
    const int tid  = threadIdx.x;
    const int wave = tid >> 6;
    const int lane = tid & 63;

    const int F0 = wave * 2048 + lane * 16;  // byte offset; 4 waves cover 8KB
    const int F1 = F0 + 1024;
    const int r0 = F0 >> 6, c0 = (F0 & 63) >> 1;  // 64B (=32 bf16) per row
    const int r1 = F1 >> 6, c1 = (F1 & 63) >> 1;
    const bf16* ga0 = Ablk + (size_t)r0 * lda + c0;
    const bf16* ga1 = Ablk + (size_t)r1 * lda + c1;
    const bf16* gb0 = Bblk + (size_t)r0 * ldb + c0;
    const bf16* gb1 = Bblk + (size_t)r1 * ldb + c1;
    bf16* lA0 = (bf16*)((char*)As + F0);
    bf16* lA1 = (bf16*)((char*)As + F1);
    bf16* lB0 = (bf16*)((char*)Bs + F0);
    bf16* lB1 = (bf16*)((char*)Bs + F1);

    const int waveM = wave >> 1, waveN = wave & 1;
    const int mrow = waveM * 64 + (lane & 15);
    const int nrow = waveN * 64 + (lane & 15);
    const int koff = (lane >> 4) * 8;

    for (int it = 0; it < kiters; ++it) {
        gload_lds16(ga0, lA0);
        gload_lds16(ga1, lA1);
        gload_lds16(gb0, lB0);
        gload_lds16(gb1, lB1);
        ga0 += BK; ga1 += BK; gb0 += BK; gb1 += BK;
        __syncthreads();

        bf16x8 af[4], bfr[4];
#pragma unroll
        for (int mi = 0; mi < 4; ++mi)
            af[mi] = *(const bf16x8*)(As + (mrow + mi * 16) * BK + koff);
#pragma unroll
        for (int ni = 0; ni < 4; ++ni)
            bfr[ni] = *(const bf16x8*)(Bs + (nrow + ni * 16) * BK + koff);
#pragma unroll
        for (int mi = 0; mi < 4; ++mi)
#pragma unroll
            for (int ni = 0; ni < 4; ++ni)
                acc[mi][ni] = __builtin_amdgcn_mfma_f32_16x16x32_bf16(
                    af[mi], bfr[ni], acc[mi][ni], 0, 0, 0);
        __syncthreads();
    }
}

// ---------------- plain GEMM: C[m][n] = A*BT^T, bf16 store -----------------
__global__ __launch_bounds__(256, 2) void k_gemm_plain(
    const bf16* __restrict__ A, long long aBatch,
    const bf16* __restrict__ BT, long long bBatch,
    bf16* __restrict__ C, long long cBatch,
    int lda, int ldb, int ldc, int kiters) {
    __shared__ __align__(16) bf16 As[128 * BK];
    __shared__ __align__(16) bf16 Bs[128 * BK];
    const int nBase = blockIdx.x * 128;
    const int mBase = blockIdx.y * 128;
    const int z = blockIdx.z;
    const bf16* Ab = A + (size_t)z * aBatch + (size_t)mBase * lda;
    const bf16* Bb = BT + (size_t)z * bBatch + (size_t)nBase * ldb;

    f32x4 acc[4][4];
    zero_acc(acc);
    mm_tile(Ab, Bb, lda, ldb, kiters, As, Bs, acc);

    const int tid = threadIdx.x, wave = tid >> 6, lane = tid & 63;
    const int waveM = wave >> 1, waveN = wave & 1;
    const int quad = lane >> 4, cno = lane & 15;
    bf16* Cb = C + (size_t)z * cBatch;
#pragma unroll
    for (int mi = 0; mi < 4; ++mi) {
        int row0 = mBase + waveM * 64 + mi * 16 + quad * 4;
#pragma unroll
        for (int ni = 0; ni < 4; ++ni) {
            int col = nBase + waveN * 64 + ni * 16 + cno;
#pragma unroll
            for (int r = 0; r < 4; ++r)
                Cb[(size_t)(row0 + r) * ldc + col] = __float2bfloat16(acc[mi][ni][r]);
        }
    }
}

// ---------------- score: packed P~ = exp(mask(Q K^T / 16)) -----------------
// P packed per batch: block-row qt starts at element 16384*qt*(qt+1)/2, rows
// have pitch (qt+1)*128. Row sums atomically added to lsum[b*4096 + q].
#define P_BATCH 8650752ll  // 528 * 16384 elements per batch
__global__ __launch_bounds__(256, 2) void k_score(
    const bf16* __restrict__ Qm, const bf16* __restrict__ Km,
    bf16* __restrict__ P, float* __restrict__ lsum) {
    const int kt = blockIdx.x, qt = blockIdx.y, b = blockIdx.z;
    if (kt > qt) return;
    __shared__ __align__(16) bf16 As[128 * BK];
    __shared__ __align__(16) bf16 Bs[128 * BK];

    const bf16* Ab = Qm + ((size_t)b * 4096 + (size_t)qt * 128) * 256;
    const bf16* Bb = Km + ((size_t)b * 4096 + (size_t)kt * 128) * 256;

    f32x4 acc[4][4];
    zero_acc(acc);
    mm_tile(Ab, Bb, 256, 256, 256 / BK, As, Bs, acc);

    const int tid = threadIdx.x, wave = tid >> 6, lane = tid & 63;
    const int waveM = wave >> 1, waveN = wave & 1;
    const int quad = lane >> 4, cno = lane & 15;
    const int pitch = (qt + 1) * 128;
    bf16* Pb = P + b * P_BATCH + (size_t)16384 * (qt * (qt + 1) / 2);
    float* lb = lsum + b * 4096;
#pragma unroll
    for (int mi = 0; mi < 4; ++mi) {
        const int lq0 = waveM * 64 + mi * 16 + quad * 4;
        float rs[4] = {0.f, 0.f, 0.f, 0.f};
#pragma unroll
        for (int ni = 0; ni < 4; ++ni) {
            const int cn = waveN * 64 + ni * 16 + cno;
            const int gk = kt * 128 + cn;
#pragma unroll
            for (int r = 0; r < 4; ++r) {
                const int gq = qt * 128 + lq0 + r;
                float s = acc[mi][ni][r] * 0.0625f;  // 1/sqrt(256)
                // ref quirk: masked OR exactly-zero score -> exp = 0
                float p = (gk <= gq && s != 0.0f) ? __expf(s) : 0.0f;
                bf16 pb = __float2bfloat16(p);
                Pb[(size_t)(lq0 + r) * pitch + gk] = pb;
                rs[r] += __bfloat162float(pb);  // sum what PV multiplies
            }
        }
#pragma unroll
        for (int r = 0; r < 4; ++r) {
            float v = rs[r];
            v += __shfl_xor(v, 1);
            v += __shfl_xor(v, 2);
            v += __shfl_xor(v, 4);
            v += __shfl_xor(v, 8);
            if (cno == 0) atomicAdd(&lb[qt * 128 + lq0 + r], v);
        }
    }
}

// --------------- PV GEMM with causal k-bound and 1/l epilogue --------------
__global__ __launch_bounds__(256, 2) void k_pv(
    const bf16* __restrict__ P, const bf16* __restrict__ VT,
    const float* __restrict__ lsum, float* __restrict__ Out) {
    __shared__ __align__(16) bf16 As[128 * BK];
    __shared__ __align__(16) bf16 Bs[128 * BK];
    const int dvBase = blockIdx.x * 128;
    const int qt = 31 - blockIdx.y;  // big tiles first
    const int b = blockIdx.z;
    const int pitch = (qt + 1) * 128;
    const bf16* Ab = P + b * P_BATCH + (size_t)16384 * (qt * (qt + 1) / 2);
    const bf16* Bb = VT + ((size_t)b * 1024 + dvBase) * 4096;

    f32x4 acc[4][4];
    zero_acc(acc);
    mm_tile(Ab, Bb, pitch, 4096, (qt + 1) * (128 / BK), As, Bs, acc);

    const int tid = threadIdx.x, wave = tid >> 6, lane = tid & 63;
    const int waveM = wave >> 1, waveN = wave & 1;
    const int quad = lane >> 4, cno = lane & 15;
    float* Ob = Out + (size_t)b * 4096 * 1024;
    const float* lb = lsum + b * 4096;
#pragma unroll
    for (int mi = 0; mi < 4; ++mi) {
        const int lq0 = waveM * 64 + mi * 16 + quad * 4;
#pragma unroll
        for (int r = 0; r < 4; ++r) {
            const int gq = qt * 128 + lq0 + r;
            const float inv = 1.0f / lb[gq];
#pragma unroll
            for (int ni = 0; ni < 4; ++ni) {
                const int col = dvBase + waveN * 64 + ni * 16 + cno;
                Ob[(size_t)gq * 1024 + col] = acc[mi][ni][r] * inv;
            }
        }
    }
}

// ------------- fused fallback (round-2 kernel, used if ws small) -----------
__global__ __launch_bounds__(256, 2) void k_attn(
    const bf16* __restrict__ Qm, const bf16* __restrict__ Km,
    const bf16* __restrict__ VT, float* __restrict__ Out) {
    __shared__ __align__(16) bf16 Qs[128 * BK];
    __shared__ __align__(16) bf16 Ks[128 * BK];
    __shared__ __align__(16) bf16 Ps[128 * PS_LD];
    __shared__ __align__(16) bf16 Vs[128 * BK];
    __shared__ float lrow[128];

    const int dvBase = blockIdx.x * 128;
    const int qt = 31 - blockIdx.y;
    const int b = blockIdx.z;
    const int tid = threadIdx.x, wave = tid >> 6, lane = tid & 63;
    const int waveM = wave >> 1, waveN = wave & 1;
    const int quad = lane >> 4, cno = lane & 15;
    const int koff = quad * 8;

    if (tid < 128) lrow[tid] = 0.f;

    f32x4 acc_o[4][4];
    zero_acc(acc_o);

    const bf16* Qtile = Qm + ((size_t)b * 4096 + (size_t)qt * 128) * 256;
    const bf16* Kbase = Km + (size_t)b * 4096 * 256;
    const bf16* Vblk  = VT + ((size_t)b * 1024 + dvBase) * 4096;

    const int F0 = wave * 2048 + lane * 16;
    const int F1 = F0 + 1024;
    const int r0 = F0 >> 6, c0 = (F0 & 63) >> 1;
    const int r1 = F1 >> 6, c1 = (F1 & 63) >> 1;

    for (int kt = 0; kt <= qt; ++kt) {
        f32x4 acc_s[4][4];
        zero_acc(acc_s);
        mm_tile(Qtile, Kbase + (size_t)kt * 128 * 256, 256, 256, 256 / BK,
                Qs, Ks, acc_s);
#pragma unroll
        for (int mi = 0; mi < 4; ++mi) {
            const int lq0 = waveM * 64 + mi * 16 + quad * 4;
            float rs[4] = {0.f, 0.f, 0.f, 0.f};
#pragma unroll
            for (int ni = 0; ni < 4; ++ni) {
                const int cn = waveN * 64 + ni * 16 + cno;
                const int gk = kt * 128 + cn;
#pragma unroll
                for (int r = 0; r < 4; ++r) {
                    const int gq = qt * 128 + lq0 + r;
                    float s = acc_s[mi][ni][r] * 0.0625f;
                    float p = (gk <= gq && s != 0.0f) ? __expf(s) : 0.0f;
                    bf16 pb = __float2bfloat16(p);
                    Ps[(lq0 + r) * PS_LD + cn] = pb;
                    rs[r] += __bfloat162float(pb);
                }
            }
#pragma unroll
            for (int r = 0; r < 4; ++r) {
                float v = rs[r];
                v += __shfl_xor(v, 1);
                v += __shfl_xor(v, 2);
                v += __shfl_xor(v, 4);
                v += __shfl_xor(v, 8);
                if (cno == 0) atomicAdd(&lrow[lq0 + r], v);
            }
        }
        __syncthreads();
#pragma unroll
        for (int c = 0; c < 4; ++c) {
            const int kcol = kt * 128 + c * 32;
            gload_lds16(Vblk + (size_t)r0 * 4096 + kcol + c0,
                        (bf16*)((char*)Vs + F0));
            gload_lds16(Vblk + (size_t)r1 * 4096 + kcol + c1,
                        (bf16*)((char*)Vs + F1));
            __syncthreads();

            bf16x8 af[4], bfr[4];
#pragma unroll
            for (int mi = 0; mi < 4; ++mi)
                af[mi] = *(const bf16x8*)(Ps + (waveM * 64 + mi * 16 + cno) * PS_LD
                                          + c * 32 + koff);
#pragma unroll
            for (int ni = 0; ni < 4; ++ni)
                bfr[ni] = *(const bf16x8*)(Vs + (waveN * 64 + ni * 16 + cno) * BK
                                           + koff);
#pragma unroll
            for (int mi = 0; mi < 4; ++mi)
#pragma unroll
                for (int ni = 0; ni < 4; ++ni)
                    acc_o[mi][ni] = __builtin_amdgcn_mfma_f32_16x16x32_bf16(
                        af[mi], bfr[ni], acc_o[mi][ni], 0, 0, 0);
            __syncthreads();
        }
    }

    float* Ob = Out + (size_t)b * 4096 * 1024;
#pragma unroll
    for (int mi = 0; mi < 4; ++mi) {
        const int lq0 = waveM * 64 + mi * 16 + quad * 4;
#pragma unroll
        for (int r = 0; r < 4; ++r) {
            const float inv = 1.0f / lrow[lq0 + r];
            const int gq = qt * 128 + lq0 + r;
#pragma unroll
            for (int ni = 0; ni < 4; ++ni) {
                const int col = dvBase + waveN * 64 + ni * 16 + cno;
                Ob[(size_t)gq * 1024 + col] = acc_o[mi][ni][r] * inv;
            }
        }
    }
}

// ----------------------------- prep kernels (f32 inputs) -------------------
__global__ void k_cast(const float4* __restrict__ in, bf16* __restrict__ out,
                       int n4) {
    int i = blockIdx.x * 256 + threadIdx.x;
    if (i >= n4) return;
    float4 v = in[i];
    bf16x4 o;
    o[0] = (__bf16)v.x; o[1] = (__bf16)v.y; o[2] = (__bf16)v.z; o[3] = (__bf16)v.w;
    *(bf16x4*)(out + 4 * (size_t)i) = o;
}

__global__ void k_transpose(const float* __restrict__ in, bf16* __restrict__ out,
                            int R, int C) {
    int idx = blockIdx.x * 256 + threadIdx.x;  // idx = c*R + r, R=1024
    if (idx >= R * C) return;
    int r = idx & (R - 1);
    int c = idx >> 10;
    out[idx] = __float2bfloat16(in[(size_t)r * C + c]);
}

__global__ void k_wvt(const float* __restrict__ Wvdown, const float* __restrict__ Wvup,
                      bf16* __restrict__ WvT) {
    int idx = blockIdx.x * 256 + threadIdx.x;  // 1M outputs
    int e = idx & 1023;
    int dv = idx >> 10;
    float acc = 0.f;
#pragma unroll 8
    for (int d = 0; d < 256; ++d)
        acc += Wvdown[e * 256 + d] * Wvup[d * 1024 + dv];
    WvT[(size_t)dv * 1024 + e] = __float2bfloat16(acc);
}

extern "C" void kernel_launch(void* const* d_in, const int* in_sizes, int n_in,
                              void* d_out, int out_size, void* d_ws, size_t ws_size,
                              hipStream_t stream) {
    const int B = 4, N = 4096, E = 1024, D = 256;
    const float* X   = (const float*)d_in[0];
    const float* Wq  = (const float*)d_in[1];
    const float* Wk  = (const float*)d_in[2];
    const float* Wvd = (const float*)d_in[3];
    const float* Wvu = (const float*)d_in[4];
    float* out = (float*)d_out;

    char* ws = (char*)d_ws;
    bf16* Xb  = (bf16*)(ws);                  // 32 MB [16384][1024]
    bf16* WqT = (bf16*)(ws + (32ll << 20));   // 512 KB [256][1024]
    bf16* WkT = (bf16*)(ws + (32ll << 20) + (512ll << 10));  // 512 KB (adj.)
    bf16* WvT = (bf16*)(ws + (33ll << 20));   // 2 MB  [1024][1024]
    bf16* Qm  = (bf16*)(ws + (35ll << 20));   // 8 MB  [16384][256]
    bf16* Km  = (bf16*)(ws + (43ll << 20));   // 8 MB  (adjacent to Qm)
    bf16* VT  = (bf16*)(ws + (51ll << 20));   // 32 MB [4][1024][4096]
    float* lsum = (float*)(ws + (83ll << 20));  // 64 KB [4][4096]
    bf16* P   = (bf16*)(ws + (84ll << 20));   // 69.2 MB packed lower-tri
    const size_t need = (84ll << 20) + (size_t)B * P_BATCH * sizeof(bf16);  // 150 MiB

    const int n4 = B * N * E / 4;
    k_cast<<<(n4 + 255) / 256, 256, 0, stream>>>((const float4*)X, Xb, n4);
    k_transpose<<<1024, 256, 0, stream>>>(Wq, WqT, 1024, 256);
    k_transpose<<<1024, 256, 0, stream>>>(Wk, WkT, 1024, 256);
    k_wvt<<<4096, 256, 0, stream>>>(Wvd, Wvu, WvT);

    // Q,K = Xb @ Wq / Xb @ Wk  (fused via z)
    k_gemm_plain<<<dim3(D / 128, (B * N) / 128, 2), 256, 0, stream>>>(
        Xb, 0, WqT, (long long)D * E, Qm, (long long)B * N * D,
        E, E, D, E / BK);

    // VT[b] = WvT @ Xb[b]^T
    k_gemm_plain<<<dim3(N / 128, E / 128, B), 256, 0, stream>>>(
        WvT, 0, Xb, (long long)N * E, VT, (long long)E * N,
        E, E, N, E / BK);

    if (ws_size >= need) {
        hipMemsetAsync(lsum, 0, (size_t)B * N * sizeof(float), stream);
        k_score<<<dim3(N / 128, N / 128, B), 256, 0, stream>>>(Qm, Km, P, lsum);
        k_pv<<<dim3(E / 128, N / 128, B), 256, 0, stream>>>(P, VT, lsum, out);
    } else {
        k_attn<<<dim3(E / 128, N / 128, B), 256, 0, stream>>>(Qm, Km, VT, out);
    }
}

// Round 6
// 407.607 us; speedup vs baseline: 2.4965x; 1.4042x over previous
//
#include <hip/hip_runtime.h>
#include <hip/hip_bf16.h>

// DotProductAttention: B=4, N=4096, E=1024, D=256. f32 in/out.
// Pipeline: cast/prep -> QKV GEMM (z=3: Q,K,Vd share A=Xb; outputs contiguous
// at Qm + z*8MiB) -> VT GEMM (VT[b] = WvupT @ Vd[b]^T, K=256) -> k_score
// (packed lower-tri P~, rowsum l) -> k_pv (O = P~ @ V / l).
// P packed by row-block (pitch (qt+1)*128): 66 MiB, aliased over dead
// Xb/weights. Total workspace need: 122 MiB + 64 KiB.
// R5 bug: Vd was at 34 MiB but z=2 output lands at Qm+2*cBatch=82 MiB -> fixed.

typedef __hip_bfloat16 bf16;
typedef __bf16 bf16x4 __attribute__((ext_vector_type(4)));
typedef __bf16 bf16x8 __attribute__((ext_vector_type(8)));
typedef float f32x4 __attribute__((ext_vector_type(4)));

#define BK 32

__device__ __forceinline__ void gload_lds16(const bf16* g, bf16* l) {
    __builtin_amdgcn_global_load_lds(
        (const __attribute__((address_space(1))) unsigned int*)g,
        (__attribute__((address_space(3))) unsigned int*)l, 16, 0, 0);
}

__device__ __forceinline__ void zero_acc(f32x4 acc[4][4]) {
#pragma unroll
    for (int mi = 0; mi < 4; ++mi)
#pragma unroll
        for (int ni = 0; ni < 4; ++ni) {
            f32x4 zf = {0.f, 0.f, 0.f, 0.f};
            acc[mi][ni] = zf;
        }
}

// C-tile accumulate: acc += A[128 x K] * BT[128 x K]^T (m97 structure).
__device__ __forceinline__ void mm_tile(const bf16* __restrict__ Ablk,
                                        const bf16* __restrict__ Bblk,
                                        int lda, int ldb, int kiters,
                                        bf16* As, bf16* Bs, f32x4 acc[4][4]) {
    const int tid  = threadIdx.x;
    const int wave = tid >> 6;
    const int lane = tid & 63;

    const int F0 = wave * 2048 + lane * 16;  // byte offset; 4 waves cover 8KB
    const int F1 = F0 + 1024;
    const int r0 = F0 >> 6, c0 = (F0 & 63) >> 1;  // 64B (=32 bf16) per row
    const int r1 = F1 >> 6, c1 = (F1 & 63) >> 1;
    const bf16* ga0 = Ablk + (size_t)r0 * lda + c0;
    const bf16* ga1 = Ablk + (size_t)r1 * lda + c1;
    const bf16* gb0 = Bblk + (size_t)r0 * ldb + c0;
    const bf16* gb1 = Bblk + (size_t)r1 * ldb + c1;
    bf16* lA0 = (bf16*)((char*)As + F0);
    bf16* lA1 = (bf16*)((char*)As + F1);
    bf16* lB0 = (bf16*)((char*)Bs + F0);
    bf16* lB1 = (bf16*)((char*)Bs + F1);

    const int waveM = wave >> 1, waveN = wave & 1;
    const int mrow = waveM * 64 + (lane & 15);
    const int nrow = waveN * 64 + (lane & 15);
    const int koff = (lane >> 4) * 8;

    for (int it = 0; it < kiters; ++it) {
        gload_lds16(ga0, lA0);
        gload_lds16(ga1, lA1);
        gload_lds16(gb0, lB0);
        gload_lds16(gb1, lB1);
        ga0 += BK; ga1 += BK; gb0 += BK; gb1 += BK;
        __syncthreads();

        bf16x8 af[4], bfr[4];
#pragma unroll
        for (int mi = 0; mi < 4; ++mi)
            af[mi] = *(const bf16x8*)(As + (mrow + mi * 16) * BK + koff);
#pragma unroll
        for (int ni = 0; ni < 4; ++ni)
            bfr[ni] = *(const bf16x8*)(Bs + (nrow + ni * 16) * BK + koff);
#pragma unroll
        for (int mi = 0; mi < 4; ++mi)
#pragma unroll
            for (int ni = 0; ni < 4; ++ni)
                acc[mi][ni] = __builtin_amdgcn_mfma_f32_16x16x32_bf16(
                    af[mi], bfr[ni], acc[mi][ni], 0, 0, 0);
        __syncthreads();
    }
}

// ---------------- plain GEMM: C[m][n] = A*BT^T, bf16 store -----------------
__global__ __launch_bounds__(256, 2) void k_gemm_plain(
    const bf16* __restrict__ A, long long aBatch,
    const bf16* __restrict__ BT, long long bBatch,
    bf16* __restrict__ C, long long cBatch,
    int lda, int ldb, int ldc, int kiters) {
    __shared__ __align__(16) bf16 As[128 * BK];
    __shared__ __align__(16) bf16 Bs[128 * BK];
    const int nBase = blockIdx.x * 128;
    const int mBase = blockIdx.y * 128;
    const int z = blockIdx.z;
    const bf16* Ab = A + (size_t)z * aBatch + (size_t)mBase * lda;
    const bf16* Bb = BT + (size_t)z * bBatch + (size_t)nBase * ldb;

    f32x4 acc[4][4];
    zero_acc(acc);
    mm_tile(Ab, Bb, lda, ldb, kiters, As, Bs, acc);

    const int tid = threadIdx.x, wave = tid >> 6, lane = tid & 63;
    const int waveM = wave >> 1, waveN = wave & 1;
    const int quad = lane >> 4, cno = lane & 15;
    bf16* Cb = C + (size_t)z * cBatch;
#pragma unroll
    for (int mi = 0; mi < 4; ++mi) {
        int row0 = mBase + waveM * 64 + mi * 16 + quad * 4;
#pragma unroll
        for (int ni = 0; ni < 4; ++ni) {
            int col = nBase + waveN * 64 + ni * 16 + cno;
#pragma unroll
            for (int r = 0; r < 4; ++r)
                Cb[(size_t)(row0 + r) * ldc + col] = __float2bfloat16(acc[mi][ni][r]);
        }
    }
}

// ---------------- score: packed P~ = exp(mask(Q K^T / 16)) -----------------
// P packed per batch: block-row qt starts at element 16384*qt*(qt+1)/2, rows
// have pitch (qt+1)*128. Row sums atomically added to lsum[b*4096 + q].
#define P_BATCH 8650752ll  // 528 * 16384 elements per batch
__global__ __launch_bounds__(256, 2) void k_score(
    const bf16* __restrict__ Qm, const bf16* __restrict__ Km,
    bf16* __restrict__ P, float* __restrict__ lsum) {
    const int kt = blockIdx.x, qt = blockIdx.y, b = blockIdx.z;
    if (kt > qt) return;
    __shared__ __align__(16) bf16 As[128 * BK];
    __shared__ __align__(16) bf16 Bs[128 * BK];

    const bf16* Ab = Qm + ((size_t)b * 4096 + (size_t)qt * 128) * 256;
    const bf16* Bb = Km + ((size_t)b * 4096 + (size_t)kt * 128) * 256;

    f32x4 acc[4][4];
    zero_acc(acc);
    mm_tile(Ab, Bb, 256, 256, 256 / BK, As, Bs, acc);

    const int tid = threadIdx.x, wave = tid >> 6, lane = tid & 63;
    const int waveM = wave >> 1, waveN = wave & 1;
    const int quad = lane >> 4, cno = lane & 15;
    const int pitch = (qt + 1) * 128;
    bf16* Pb = P + b * P_BATCH + (size_t)16384 * (qt * (qt + 1) / 2);
    float* lb = lsum + b * 4096;
#pragma unroll
    for (int mi = 0; mi < 4; ++mi) {
        const int lq0 = waveM * 64 + mi * 16 + quad * 4;
        float rs[4] = {0.f, 0.f, 0.f, 0.f};
#pragma unroll
        for (int ni = 0; ni < 4; ++ni) {
            const int cn = waveN * 64 + ni * 16 + cno;
            const int gk = kt * 128 + cn;
#pragma unroll
            for (int r = 0; r < 4; ++r) {
                const int gq = qt * 128 + lq0 + r;
                float s = acc[mi][ni][r] * 0.0625f;  // 1/sqrt(256)
                // ref quirk: masked OR exactly-zero score -> exp = 0
                float p = (gk <= gq && s != 0.0f) ? __expf(s) : 0.0f;
                bf16 pb = __float2bfloat16(p);
                Pb[(size_t)(lq0 + r) * pitch + gk] = pb;
                rs[r] += __bfloat162float(pb);  // sum what PV multiplies
            }
        }
#pragma unroll
        for (int r = 0; r < 4; ++r) {
            float v = rs[r];
            v += __shfl_xor(v, 1);
            v += __shfl_xor(v, 2);
            v += __shfl_xor(v, 4);
            v += __shfl_xor(v, 8);
            if (cno == 0) atomicAdd(&lb[qt * 128 + lq0 + r], v);
        }
    }
}

// --------------- PV GEMM with causal k-bound and 1/l epilogue --------------
__global__ __launch_bounds__(256, 2) void k_pv(
    const bf16* __restrict__ P, const bf16* __restrict__ VT,
    const float* __restrict__ lsum, float* __restrict__ Out) {
    __shared__ __align__(16) bf16 As[128 * BK];
    __shared__ __align__(16) bf16 Bs[128 * BK];
    const int dvBase = blockIdx.x * 128;
    const int qt = 31 - blockIdx.y;  // big tiles first
    const int b = blockIdx.z;
    const int pitch = (qt + 1) * 128;
    const bf16* Ab = P + b * P_BATCH + (size_t)16384 * (qt * (qt + 1) / 2);
    const bf16* Bb = VT + ((size_t)b * 1024 + dvBase) * 4096;

    f32x4 acc[4][4];
    zero_acc(acc);
    mm_tile(Ab, Bb, pitch, 4096, (qt + 1) * (128 / BK), As, Bs, acc);

    const int tid = threadIdx.x, wave = tid >> 6, lane = tid & 63;
    const int waveM = wave >> 1, waveN = wave & 1;
    const int quad = lane >> 4, cno = lane & 15;
    float* Ob = Out + (size_t)b * 4096 * 1024;
    const float* lb = lsum + b * 4096;
#pragma unroll
    for (int mi = 0; mi < 4; ++mi) {
        const int lq0 = waveM * 64 + mi * 16 + quad * 4;
#pragma unroll
        for (int r = 0; r < 4; ++r) {
            const int gq = qt * 128 + lq0 + r;
            const float inv = 1.0f / lb[gq];
#pragma unroll
            for (int ni = 0; ni < 4; ++ni) {
                const int col = dvBase + waveN * 64 + ni * 16 + cno;
                Ob[(size_t)gq * 1024 + col] = acc[mi][ni][r] * inv;
            }
        }
    }
}

// ----------------------------- prep kernels (f32 inputs) -------------------
__global__ void k_cast(const float4* __restrict__ in, bf16* __restrict__ out,
                       int n4) {
    int i = blockIdx.x * 256 + threadIdx.x;
    if (i >= n4) return;
    float4 v = in[i];
    bf16x4 o;
    o[0] = (__bf16)v.x; o[1] = (__bf16)v.y; o[2] = (__bf16)v.z; o[3] = (__bf16)v.w;
    *(bf16x4*)(out + 4 * (size_t)i) = o;
}

// out[idx] = in[(idx & mask) * tstride + (idx >> shift)]; n = total elements.
__global__ void k_transpose(const float* __restrict__ in, bf16* __restrict__ out,
                            int n, int mask, int shift, int tstride) {
    int idx = blockIdx.x * 256 + threadIdx.x;
    if (idx >= n) return;
    out[idx] = __float2bfloat16(in[(size_t)(idx & mask) * tstride + (idx >> shift)]);
}

extern "C" void kernel_launch(void* const* d_in, const int* in_sizes, int n_in,
                              void* d_out, int out_size, void* d_ws, size_t ws_size,
                              hipStream_t stream) {
    const int B = 4, N = 4096, E = 1024, D = 256;
    const float* X   = (const float*)d_in[0];  // [4,4096,1024]
    const float* Wq  = (const float*)d_in[1];  // [1024,256]
    const float* Wk  = (const float*)d_in[2];  // [1024,256]
    const float* Wvd = (const float*)d_in[3];  // [1024,256]
    const float* Wvu = (const float*)d_in[4];  // [256,1024]
    float* out = (float*)d_out;                // [4,4096,1024]

    // ---- workspace layout (122 MiB + 64 KiB; P overlays dead Xb/weights) ---
    const long long MiB = 1ll << 20;
    char* ws = (char*)d_ws;
    bf16* Xb     = (bf16*)(ws);                       // [ 0,32)  [16384][1024]
    bf16* WqT    = (bf16*)(ws + 32 * MiB);            // 512 KiB  [256][1024]
    bf16* WkT    = (bf16*)(ws + 32 * MiB + 524288);   // 512 KiB (contiguous!)
    bf16* WvdT   = (bf16*)(ws + 32 * MiB + 1048576);  // 512 KiB (contiguous!)
    bf16* WvupT  = (bf16*)(ws + 32 * MiB + 1572864);  // 512 KiB  [1024][256]
    bf16* P      = (bf16*)(ws);                       // [ 0,66)  packed tri
    bf16* Qm     = (bf16*)(ws + 66 * MiB);            // [66,74)  [16384][256]
    bf16* Km     = (bf16*)(ws + 74 * MiB);            // [74,82)  = Qm+cBatch
    bf16* Vd     = (bf16*)(ws + 82 * MiB);            // [82,90)  = Qm+2*cBatch
    bf16* VT     = (bf16*)(ws + 90 * MiB);            // [90,122) [4][1024][4096]
    float* lsum  = (float*)(ws + 122 * MiB);          // 64 KiB   [4][4096]
    // lifetime: Xb/W*T dead before k_score writes P (alias [0,66) ok);
    // Vd dead after VT GEMM (not overlapped by P anyway).

    const int n4 = B * N * E / 4;
    k_cast<<<(n4 + 255) / 256, 256, 0, stream>>>((const float4*)X, Xb, n4);
    // WqT[d][e] = Wq[e][d]: idx=d*1024+e -> e=idx&1023, d=idx>>10, stride 256
    k_transpose<<<1024, 256, 0, stream>>>(Wq,  WqT,  E * D, 1023, 10, 256);
    k_transpose<<<1024, 256, 0, stream>>>(Wk,  WkT,  E * D, 1023, 10, 256);
    k_transpose<<<1024, 256, 0, stream>>>(Wvd, WvdT, E * D, 1023, 10, 256);
    // WvupT[dv][d] = Wvu[d][dv]: idx=dv*256+d -> d=idx&255, dv=idx>>8, str 1024
    k_transpose<<<1024, 256, 0, stream>>>(Wvu, WvupT, D * E, 255, 8, 1024);
    hipMemsetAsync(lsum, 0, (size_t)B * N * sizeof(float), stream);

    // Q,K,Vd = Xb @ {Wq,Wk,Wvdown}  (z=3: A shared, BT/C strided; C outputs
    // land at Qm + z*8MiB = Qm, Km, Vd -- layout above matches)
    k_gemm_plain<<<dim3(D / 128, (B * N) / 128, 3), 256, 0, stream>>>(
        Xb, 0, WqT, (long long)D * E, Qm, (long long)B * N * D,
        E, E, D, E / BK);

    // VT[b][dv][n] = sum_d WvupT[dv][d] * Vd[b][n][d]   (K=256)
    k_gemm_plain<<<dim3(N / 128, E / 128, B), 256, 0, stream>>>(
        WvupT, 0, Vd, (long long)N * D, VT, (long long)E * N,
        D, D, N, D / BK);

    // P~ = exp(mask(Q K^T / 16)) packed; row sums -> lsum
    k_score<<<dim3(N / 128, N / 128, B), 256, 0, stream>>>(Qm, Km, P, lsum);

    // Out = (P~ @ V) / l
    k_pv<<<dim3(E / 128, N / 128, B), 256, 0, stream>>>(P, VT, lsum, out);
}

// Round 7
// 353.898 us; speedup vs baseline: 2.8754x; 1.1518x over previous
//
#include <hip/hip_runtime.h>
#include <hip/hip_bf16.h>

// DotProductAttention: B=4, N=4096, E=1024, D=256. f32 in/out.
// Pipeline: cast/prep -> QKV GEMM (z=3) -> VT GEMM -> k_score (packed
// lower-tri P~, rowsum l) -> k_pv (O = P~ @ V / l).
// R7: load-balance fixes. k_pv pairs qt=(31-p, p) per block -> every block
// does exactly 132 k-steps (was: per-CU work ∝ qt+1, 2x makespan).
// k_score enumerates only the 528 lower-tri tiles per batch (was: fixed-kt
// per CU, half the grid dead).

typedef __hip_bfloat16 bf16;
typedef __bf16 bf16x4 __attribute__((ext_vector_type(4)));
typedef __bf16 bf16x8 __attribute__((ext_vector_type(8)));
typedef float f32x4 __attribute__((ext_vector_type(4)));

#define BK 32

__device__ __forceinline__ void gload_lds16(const bf16* g, bf16* l) {
    __builtin_amdgcn_global_load_lds(
        (const __attribute__((address_space(1))) unsigned int*)g,
        (__attribute__((address_space(3))) unsigned int*)l, 16, 0, 0);
}

__device__ __forceinline__ void zero_acc(f32x4 acc[4][4]) {
#pragma unroll
    for (int mi = 0; mi < 4; ++mi)
#pragma unroll
        for (int ni = 0; ni < 4; ++ni) {
            f32x4 zf = {0.f, 0.f, 0.f, 0.f};
            acc[mi][ni] = zf;
        }
}

// C-tile accumulate: acc += A[128 x K] * BT[128 x K]^T (m97 structure).
__device__ __forceinline__ void mm_tile(const bf16* __restrict__ Ablk,
                                        const bf16* __restrict__ Bblk,
                                        int lda, int ldb, int kiters,
                                        bf16* As, bf16* Bs, f32x4 acc[4][4]) {
    const int tid  = threadIdx.x;
    const int wave = tid >> 6;
    const int lane = tid & 63;

    const int F0 = wave * 2048 + lane * 16;  // byte offset; 4 waves cover 8KB
    const int F1 = F0 + 1024;
    const int r0 = F0 >> 6, c0 = (F0 & 63) >> 1;  // 64B (=32 bf16) per row
    const int r1 = F1 >> 6, c1 = (F1 & 63) >> 1;
    const bf16* ga0 = Ablk + (size_t)r0 * lda + c0;
    const bf16* ga1 = Ablk + (size_t)r1 * lda + c1;
    const bf16* gb0 = Bblk + (size_t)r0 * ldb + c0;
    const bf16* gb1 = Bblk + (size_t)r1 * ldb + c1;
    bf16* lA0 = (bf16*)((char*)As + F0);
    bf16* lA1 = (bf16*)((char*)As + F1);
    bf16* lB0 = (bf16*)((char*)Bs + F0);
    bf16* lB1 = (bf16*)((char*)Bs + F1);

    const int waveM = wave >> 1, waveN = wave & 1;
    const int mrow = waveM * 64 + (lane & 15);
    const int nrow = waveN * 64 + (lane & 15);
    const int koff = (lane >> 4) * 8;

    for (int it = 0; it < kiters; ++it) {
        gload_lds16(ga0, lA0);
        gload_lds16(ga1, lA1);
        gload_lds16(gb0, lB0);
        gload_lds16(gb1, lB1);
        ga0 += BK; ga1 += BK; gb0 += BK; gb1 += BK;
        __syncthreads();

        bf16x8 af[4], bfr[4];
#pragma unroll
        for (int mi = 0; mi < 4; ++mi)
            af[mi] = *(const bf16x8*)(As + (mrow + mi * 16) * BK + koff);
#pragma unroll
        for (int ni = 0; ni < 4; ++ni)
            bfr[ni] = *(const bf16x8*)(Bs + (nrow + ni * 16) * BK + koff);
#pragma unroll
        for (int mi = 0; mi < 4; ++mi)
#pragma unroll
            for (int ni = 0; ni < 4; ++ni)
                acc[mi][ni] = __builtin_amdgcn_mfma_f32_16x16x32_bf16(
                    af[mi], bfr[ni], acc[mi][ni], 0, 0, 0);
        __syncthreads();
    }
}

// ---------------- plain GEMM: C[m][n] = A*BT^T, bf16 store -----------------
__global__ __launch_bounds__(256, 2) void k_gemm_plain(
    const bf16* __restrict__ A, long long aBatch,
    const bf16* __restrict__ BT, long long bBatch,
    bf16* __restrict__ C, long long cBatch,
    int lda, int ldb, int ldc, int kiters) {
    __shared__ __align__(16) bf16 As[128 * BK];
    __shared__ __align__(16) bf16 Bs[128 * BK];
    const int nBase = blockIdx.x * 128;
    const int mBase = blockIdx.y * 128;
    const int z = blockIdx.z;
    const bf16* Ab = A + (size_t)z * aBatch + (size_t)mBase * lda;
    const bf16* Bb = BT + (size_t)z * bBatch + (size_t)nBase * ldb;

    f32x4 acc[4][4];
    zero_acc(acc);
    mm_tile(Ab, Bb, lda, ldb, kiters, As, Bs, acc);

    const int tid = threadIdx.x, wave = tid >> 6, lane = tid & 63;
    const int waveM = wave >> 1, waveN = wave & 1;
    const int quad = lane >> 4, cno = lane & 15;
    bf16* Cb = C + (size_t)z * cBatch;
#pragma unroll
    for (int mi = 0; mi < 4; ++mi) {
        int row0 = mBase + waveM * 64 + mi * 16 + quad * 4;
#pragma unroll
        for (int ni = 0; ni < 4; ++ni) {
            int col = nBase + waveN * 64 + ni * 16 + cno;
#pragma unroll
            for (int r = 0; r < 4; ++r)
                Cb[(size_t)(row0 + r) * ldc + col] = __float2bfloat16(acc[mi][ni][r]);
        }
    }
}

// ---------------- score: packed P~ = exp(mask(Q K^T / 16)) -----------------
// Only the 528 lower-tri tiles per batch are launched; flat index f decodes
// to (qt, kt). P packed per batch: block-row qt starts at element
// 16384*qt*(qt+1)/2, rows have pitch (qt+1)*128. Row sums -> lsum atomics.
#define P_BATCH 8650752ll  // 528 * 16384 elements per batch
__global__ __launch_bounds__(256, 2) void k_score(
    const bf16* __restrict__ Qm, const bf16* __restrict__ Km,
    bf16* __restrict__ P, float* __restrict__ lsum) {
    const int f = blockIdx.x, b = blockIdx.z;
    // decode f -> (qt, kt): qt = floor((sqrt(8f+1)-1)/2), kt = f - tri(qt)
    int qt = (int)((sqrtf(8.f * (float)f + 1.f) - 1.f) * 0.5f);
    while ((qt + 1) * (qt + 2) / 2 <= f) ++qt;
    while (qt * (qt + 1) / 2 > f) --qt;
    const int kt = f - qt * (qt + 1) / 2;

    __shared__ __align__(16) bf16 As[128 * BK];
    __shared__ __align__(16) bf16 Bs[128 * BK];

    const bf16* Ab = Qm + ((size_t)b * 4096 + (size_t)qt * 128) * 256;
    const bf16* Bb = Km + ((size_t)b * 4096 + (size_t)kt * 128) * 256;

    f32x4 acc[4][4];
    zero_acc(acc);
    mm_tile(Ab, Bb, 256, 256, 256 / BK, As, Bs, acc);

    const int tid = threadIdx.x, wave = tid >> 6, lane = tid & 63;
    const int waveM = wave >> 1, waveN = wave & 1;
    const int quad = lane >> 4, cno = lane & 15;
    const int pitch = (qt + 1) * 128;
    bf16* Pb = P + b * P_BATCH + (size_t)16384 * (qt * (qt + 1) / 2);
    float* lb = lsum + b * 4096;
#pragma unroll
    for (int mi = 0; mi < 4; ++mi) {
        const int lq0 = waveM * 64 + mi * 16 + quad * 4;
        float rs[4] = {0.f, 0.f, 0.f, 0.f};
#pragma unroll
        for (int ni = 0; ni < 4; ++ni) {
            const int cn = waveN * 64 + ni * 16 + cno;
            const int gk = kt * 128 + cn;
#pragma unroll
            for (int r = 0; r < 4; ++r) {
                const int gq = qt * 128 + lq0 + r;
                float s = acc[mi][ni][r] * 0.0625f;  // 1/sqrt(256)
                // ref quirk: masked OR exactly-zero score -> exp = 0
                float p = (gk <= gq && s != 0.0f) ? __expf(s) : 0.0f;
                bf16 pb = __float2bfloat16(p);
                Pb[(size_t)(lq0 + r) * pitch + gk] = pb;
                rs[r] += __bfloat162float(pb);  // sum what PV multiplies
            }
        }
#pragma unroll
        for (int r = 0; r < 4; ++r) {
            float v = rs[r];
            v += __shfl_xor(v, 1);
            v += __shfl_xor(v, 2);
            v += __shfl_xor(v, 4);
            v += __shfl_xor(v, 8);
            if (cno == 0) atomicAdd(&lb[qt * 128 + lq0 + r], v);
        }
    }
}

// --------------- PV GEMM, qt-paired for perfect balance --------------------
// Block (dv, p, b) processes qt = 31-p then qt = p: exactly 132 k-steps per
// block. linear%8 == dv keeps the VT slice XCD-local.
__global__ __launch_bounds__(256, 2) void k_pv(
    const bf16* __restrict__ P, const bf16* __restrict__ VT,
    const float* __restrict__ lsum, float* __restrict__ Out) {
    __shared__ __align__(16) bf16 As[128 * BK];
    __shared__ __align__(16) bf16 Bs[128 * BK];
    const int dvBase = blockIdx.x * 128;
    const int pair = blockIdx.y;  // 0..15
    const int b = blockIdx.z;
    const int tid = threadIdx.x, wave = tid >> 6, lane = tid & 63;
    const int waveM = wave >> 1, waveN = wave & 1;
    const int quad = lane >> 4, cno = lane & 15;

    const bf16* Bb = VT + ((size_t)b * 1024 + dvBase) * 4096;
    float* Ob = Out + (size_t)b * 4096 * 1024;
    const float* lb = lsum + b * 4096;

    for (int half = 0; half < 2; ++half) {
        const int qt = half ? pair : (31 - pair);
        const int pitch = (qt + 1) * 128;
        const bf16* Ab = P + b * P_BATCH + (size_t)16384 * (qt * (qt + 1) / 2);

        f32x4 acc[4][4];
        zero_acc(acc);
        mm_tile(Ab, Bb, pitch, 4096, (qt + 1) * (128 / BK), As, Bs, acc);

#pragma unroll
        for (int mi = 0; mi < 4; ++mi) {
            const int lq0 = waveM * 64 + mi * 16 + quad * 4;
#pragma unroll
            for (int r = 0; r < 4; ++r) {
                const int gq = qt * 128 + lq0 + r;
                const float inv = 1.0f / lb[gq];
#pragma unroll
                for (int ni = 0; ni < 4; ++ni) {
                    const int col = dvBase + waveN * 64 + ni * 16 + cno;
                    Ob[(size_t)gq * 1024 + col] = acc[mi][ni][r] * inv;
                }
            }
        }
    }
}

// ----------------------------- prep kernels (f32 inputs) -------------------
__global__ void k_cast(const float4* __restrict__ in, bf16* __restrict__ out,
                       int n4) {
    int i = blockIdx.x * 256 + threadIdx.x;
    if (i >= n4) return;
    float4 v = in[i];
    bf16x4 o;
    o[0] = (__bf16)v.x; o[1] = (__bf16)v.y; o[2] = (__bf16)v.z; o[3] = (__bf16)v.w;
    *(bf16x4*)(out + 4 * (size_t)i) = o;
}

// out[idx] = in[(idx & mask) * tstride + (idx >> shift)]; n = total elements.
__global__ void k_transpose(const float* __restrict__ in, bf16* __restrict__ out,
                            int n, int mask, int shift, int tstride) {
    int idx = blockIdx.x * 256 + threadIdx.x;
    if (idx >= n) return;
    out[idx] = __float2bfloat16(in[(size_t)(idx & mask) * tstride + (idx >> shift)]);
}

extern "C" void kernel_launch(void* const* d_in, const int* in_sizes, int n_in,
                              void* d_out, int out_size, void* d_ws, size_t ws_size,
                              hipStream_t stream) {
    const int B = 4, N = 4096, E = 1024, D = 256;
    const float* X   = (const float*)d_in[0];  // [4,4096,1024]
    const float* Wq  = (const float*)d_in[1];  // [1024,256]
    const float* Wk  = (const float*)d_in[2];  // [1024,256]
    const float* Wvd = (const float*)d_in[3];  // [1024,256]
    const float* Wvu = (const float*)d_in[4];  // [256,1024]
    float* out = (float*)d_out;                // [4,4096,1024]

    // ---- workspace layout (122 MiB + 64 KiB; P overlays dead Xb/weights) ---
    const long long MiB = 1ll << 20;
    char* ws = (char*)d_ws;
    bf16* Xb     = (bf16*)(ws);                       // [ 0,32)  [16384][1024]
    bf16* WqT    = (bf16*)(ws + 32 * MiB);            // 512 KiB  [256][1024]
    bf16* WkT    = (bf16*)(ws + 32 * MiB + 524288);   // 512 KiB (contiguous!)
    bf16* WvdT   = (bf16*)(ws + 32 * MiB + 1048576);  // 512 KiB (contiguous!)
    bf16* WvupT  = (bf16*)(ws + 32 * MiB + 1572864);  // 512 KiB  [1024][256]
    bf16* P      = (bf16*)(ws);                       // [ 0,66)  packed tri
    bf16* Qm     = (bf16*)(ws + 66 * MiB);            // [66,74)  [16384][256]
    bf16* Km     = (bf16*)(ws + 74 * MiB);            // [74,82)  = Qm+cBatch
    bf16* Vd     = (bf16*)(ws + 82 * MiB);            // [82,90)  = Qm+2*cBatch
    bf16* VT     = (bf16*)(ws + 90 * MiB);            // [90,122) [4][1024][4096]
    float* lsum  = (float*)(ws + 122 * MiB);          // 64 KiB   [4][4096]
    // lifetime: Xb/W*T dead before k_score writes P (alias [0,66) ok)

    const int n4 = B * N * E / 4;
    k_cast<<<(n4 + 255) / 256, 256, 0, stream>>>((const float4*)X, Xb, n4);
    // WqT[d][e] = Wq[e][d]: idx=d*1024+e -> e=idx&1023, d=idx>>10, stride 256
    k_transpose<<<1024, 256, 0, stream>>>(Wq,  WqT,  E * D, 1023, 10, 256);
    k_transpose<<<1024, 256, 0, stream>>>(Wk,  WkT,  E * D, 1023, 10, 256);
    k_transpose<<<1024, 256, 0, stream>>>(Wvd, WvdT, E * D, 1023, 10, 256);
    // WvupT[dv][d] = Wvu[d][dv]: idx=dv*256+d -> d=idx&255, dv=idx>>8, str 1024
    k_transpose<<<1024, 256, 0, stream>>>(Wvu, WvupT, D * E, 255, 8, 1024);
    hipMemsetAsync(lsum, 0, (size_t)B * N * sizeof(float), stream);

    // Q,K,Vd = Xb @ {Wq,Wk,Wvdown}  (z=3: outputs at Qm + z*8MiB)
    k_gemm_plain<<<dim3(D / 128, (B * N) / 128, 3), 256, 0, stream>>>(
        Xb, 0, WqT, (long long)D * E, Qm, (long long)B * N * D,
        E, E, D, E / BK);

    // VT[b][dv][n] = sum_d WvupT[dv][d] * Vd[b][n][d]   (K=256)
    k_gemm_plain<<<dim3(N / 128, E / 128, B), 256, 0, stream>>>(
        WvupT, 0, Vd, (long long)N * D, VT, (long long)E * N,
        D, D, N, D / BK);

    // P~ = exp(mask(Q K^T / 16)) packed; row sums -> lsum (528 tri tiles/b)
    k_score<<<dim3(528, 1, B), 256, 0, stream>>>(Qm, Km, P, lsum);

    // Out = (P~ @ V) / l  (qt-paired: every block = 132 k-steps)
    k_pv<<<dim3(E / 128, 16, B), 256, 0, stream>>>(P, VT, lsum, out);
}